// Round 2
// baseline (77.565 us; speedup 1.0000x reference)
//
#include <hip/hip_runtime.h>
#include <hip/hip_bf16.h>

// Problem constants (from reference)
constexpr int S = 256;          // N_SINES
constexpr int N = 512;          // control points
constexpr int R = 32;           // RESAMPLING_FACTOR
constexpr int OUT_N = N * R;    // 16384 output samples per batch

// ---------------------------------------------------------------------------
// Kernel 1: per-(b,s) block-prefix scan.
// G[row][n] = 16*f0 + sum_{m<n} 16*(f_m + f_{m+1})   (units: Hz-samples; the
// 2*pi/FS scale cancels later since frac(phase/2pi) = frac(freqsum/44100)).
// One block per row (b*S+s), 512 threads, Hillis-Steele scan in LDS (fp64).
// ---------------------------------------------------------------------------
__global__ __launch_bounds__(512) void block_prefix_kernel(
    const float* __restrict__ freq, double* __restrict__ G) {
  const int row = blockIdx.x;          // b*S + s
  const int n = threadIdx.x;           // 0..511
  const float* f = freq + (size_t)row * N;

  __shared__ double sh[N];
  float fn  = f[n];
  float fnp = (n < N - 1) ? f[n + 1] : 0.0f;
  sh[n] = (n < N - 1) ? 16.0 * ((double)fn + (double)fnp) : 0.0;
  __syncthreads();

  for (int off = 1; off < N; off <<= 1) {
    double add = (n >= off) ? sh[n - off] : 0.0;
    __syncthreads();
    sh[n] += add;
    __syncthreads();
  }

  double g = 16.0 * (double)f[0] + ((n == 0) ? 0.0 : sh[n - 1]);
  G[(size_t)row * N + n] = g;
}

// ---------------------------------------------------------------------------
// Kernel 2: synthesize output samples (float32 output — reference dtype).
// Each block handles 64 consecutive output samples of one batch; the 4 waves
// (256 threads) each cover 64 of the 256 sines, then LDS-reduce.
//
// For sample j in batch b:
//   j <  16          : P = (j+1)*f0                                    (clip)
//   16 <= j < 16368  : n=(j-16)>>5, k=(j-16)&31,
//                      P = G[n] + (k+1)*f_n + (f_{n+1}-f_n)*(k+1)^2/64
//   j >= 16368       : P = G[511] + (j-16367)*f_511                    (clip)
// phase (radians) = P * 2pi/44100  ->  revolutions r = frac(P/44100).
// amp upsample: a_n + (a_{n+1}-a_n)*w, w=(k+0.5)/32 (0 in clip regions).
// sin computed via v_sin_f32 (input in revolutions) on fp64-frac'd phase.
// ---------------------------------------------------------------------------
__global__ __launch_bounds__(256) void synth_kernel(
    const float* __restrict__ freq, const float* __restrict__ amp,
    const double* __restrict__ G, float* __restrict__ out) {
  const int tid = threadIdx.x;
  const int split = tid >> 6;                 // wave id 0..3 -> sine chunk
  const int samp = tid & 63;
  const int gid = blockIdx.x * 64 + samp;     // global output sample id
  const int b = gid >> 14;                    // / OUT_N
  const int j = gid & (OUT_N - 1);

  int n;
  double c1, c2, gsel;
  float wa;
  if (j < 16) {                     // leading clip region: value = f0, a0
    n = 0; c1 = (double)(j + 1); c2 = 0.0; gsel = 0.0; wa = 0.0f;
  } else if (j >= OUT_N - 16) {     // trailing clip region: value = f511, a511
    n = N - 1; c1 = (double)(j - (OUT_N - 16) + 1); c2 = 0.0; gsel = 1.0; wa = 0.0f;
  } else {
    const int jj = j - 16;
    n = jj >> 5;
    const int k = jj & 31;
    c1 = (double)(k + 1);
    c2 = (double)((k + 1) * (k + 1)) * (1.0 / 64.0);
    gsel = 1.0;
    wa = ((float)k + 0.5f) * (1.0f / 32.0f);
  }
  const int dn1 = min(n + 1, N - 1) - n;      // offset to f_{n+1} (0 at tail)

  const float* frow = freq + ((size_t)b * S) * N + n;
  const float* arow = amp  + ((size_t)b * S) * N + n;
  const double* grow = G   + ((size_t)b * S) * N + n;

  const double inv_fs = 1.0 / 44100.0;        // rev per Hz-sample
  float acc = 0.0f;
  const int s0 = split * (S / 4);
  #pragma unroll 4
  for (int s = s0; s < s0 + S / 4; ++s) {
    const float* fp = frow + (size_t)s * N;
    const float* ap = arow + (size_t)s * N;
    const float fn  = fp[0];
    const float fn1 = fp[dn1];
    const float an  = ap[0];
    const float an1 = ap[dn1];
    const double g = grow[(size_t)s * N];

    double ph = fma(gsel, g, fma(c1, (double)fn,
                                 c2 * ((double)fn1 - (double)fn)));
    double r = ph * inv_fs;                   // revolutions
    r -= floor(r);                            // frac -> [0,1)
    const float sv = __builtin_amdgcn_sinf((float)r);  // sin(2*pi*r)
    const float av = fmaf(an1 - an, wa, an);
    acc = fmaf(av, sv, acc);
  }

  __shared__ float red[256];
  red[tid] = acc;
  __syncthreads();
  if (tid < 64) {
    const float v = red[tid] + red[tid + 64] + red[tid + 128] + red[tid + 192];
    out[gid] = v;
  }
}

// ---------------------------------------------------------------------------
extern "C" void kernel_launch(void* const* d_in, const int* in_sizes, int n_in,
                              void* d_out, int out_size, void* d_ws, size_t ws_size,
                              hipStream_t stream) {
  const float* freq = (const float*)d_in[0];
  const float* amp  = (const float*)d_in[1];
  float* out = (float*)d_out;
  double* G = (double*)d_ws;                  // [B][S][N] fp64 = 4 MiB at B=4

  const int B = in_sizes[0] / (S * N);        // 4

  block_prefix_kernel<<<dim3(B * S), dim3(512), 0, stream>>>(freq, G);
  synth_kernel<<<dim3(B * OUT_N / 64), dim3(256), 0, stream>>>(freq, amp, G, out);
}